// Round 1
// baseline (704.992 us; speedup 1.0000x reference)
//
#include <hip/hip_runtime.h>
#include <math.h>

// Problem constants: B=2, C=CIN=COUT=64, S=H=W=128, K=3, G=4 (groups are a no-op)
constexpr int HW   = 128 * 128;            // 16384
constexpr int NCHW = 2 * 64 * HW;          // 2097152

// Workspace layout (float element offsets). Z overlays q/k (dead after attn),
// P overlays v/out (dead after gemm64), R overlays out2 (written later).
constexpr size_t OFF_Q    = 0;             // q   [2,64,128,128]
constexpr size_t OFF_K    = 2097152;       // k
constexpr size_t OFF_V    = 4194304;       // v
constexpr size_t OFF_OUT  = 6291456;       // attention out
constexpr size_t OFF_OUT2 = 8388608;       // out2 (earlier: R intermediate)
constexpr size_t OFF_R    = 8388608;
constexpr size_t OFF_F    = 10485760;      // F[b,kh,kw] complex  (65536 floats)
constexpr size_t OFF_M    = 10551296;      // combined conv matrix (4096)
constexpr size_t OFF_BC   = 10555392;      // combined bias (64)
constexpr size_t OFF_Z    = 0;             // Z[b,c,kh,x] complex (4194304 floats)
constexpr size_t OFF_P    = 4194304;       // wsum partials [2][64][16384] complex (4194304 floats)

// ---------------- fused q,k,v 1x1 convs: one fs stage, 3 weight mats in LDS ---------------------
__global__ __launch_bounds__(256) void k_qkv(
    const float* __restrict__ fs,
    const float* __restrict__ w_q, const float* __restrict__ w_k, const float* __restrict__ w_v,
    float* __restrict__ q, float* __restrict__ kk, float* __restrict__ vv)
{
    __shared__ float xs[64][64];       // [ci][px]
    __shared__ float wl[3][64][65];    // [q/k/v][co][ci] padded
    int blk = blockIdx.x;              // 2*256 blocks, 64 px each
    int b = blk >> 8;
    int px0 = (blk & 255) << 6;
    int t = threadIdx.x;
    for (int i = t; i < 4096; i += 256) {
        int r = i >> 6, cix = i & 63;
        wl[0][r][cix] = w_q[i];
        wl[1][r][cix] = w_k[i];
        wl[2][r][cix] = w_v[i];
        xs[r][cix] = fs[b * (64 * HW) + r * HW + px0 + cix];
    }
    __syncthreads();
    int pxq = t & 15, rq = t >> 4;     // 4 px, 4 rows per thread
    float aq[4][4], ak[4][4], av[4][4];
    #pragma unroll
    for (int i = 0; i < 4; i++)
        for (int j = 0; j < 4; j++) { aq[i][j] = 0.f; ak[i][j] = 0.f; av[i][j] = 0.f; }
    for (int ci = 0; ci < 64; ci++) {
        float4 xv = *reinterpret_cast<const float4*>(&xs[ci][pxq * 4]);
        #pragma unroll
        for (int i = 0; i < 4; i++) {
            float wq_ = wl[0][rq * 4 + i][ci];
            float wk_ = wl[1][rq * 4 + i][ci];
            float wv_ = wl[2][rq * 4 + i][ci];
            aq[i][0] += wq_ * xv.x; aq[i][1] += wq_ * xv.y; aq[i][2] += wq_ * xv.z; aq[i][3] += wq_ * xv.w;
            ak[i][0] += wk_ * xv.x; ak[i][1] += wk_ * xv.y; ak[i][2] += wk_ * xv.z; ak[i][3] += wk_ * xv.w;
            av[i][0] += wv_ * xv.x; av[i][1] += wv_ * xv.y; av[i][2] += wv_ * xv.z; av[i][3] += wv_ * xv.w;
        }
    }
    #pragma unroll
    for (int i = 0; i < 4; i++) {
        int co = rq * 4 + i;
        size_t base = (size_t)b * (64 * HW) + (size_t)co * HW + px0 + pxq * 4;
        *reinterpret_cast<float4*>(q  + base) = make_float4(aq[i][0], aq[i][1], aq[i][2], aq[i][3]);
        *reinterpret_cast<float4*>(kk + base) = make_float4(ak[i][0], ak[i][1], ak[i][2], ak[i][3]);
        *reinterpret_cast<float4*>(vv + base) = make_float4(av[i][0], av[i][1], av[i][2], av[i][3]);
    }
}

// ---------------- generic 64x64 1x1-conv GEMM: y[b,co,p] = sum_ci w[co,ci] x[b,ci,p] (+bias) ----
__global__ __launch_bounds__(256) void k_gemm64(
    const float* __restrict__ x, const float* __restrict__ w,
    const float* __restrict__ bias, float* __restrict__ y)
{
    __shared__ float xs[64][64];   // [ci][px]
    __shared__ float wl[64][65];   // [co][ci] padded
    int blk = blockIdx.x;          // 2*256 blocks, 64 px each
    int b = blk >> 8;
    int px0 = (blk & 255) << 6;
    int t = threadIdx.x;
    for (int i = t; i < 4096; i += 256) {
        int r = i >> 6, cix = i & 63;
        wl[r][cix] = w[i];
        xs[r][cix] = x[b * (64 * HW) + r * HW + px0 + cix];
    }
    __syncthreads();
    int pxq = t & 15, rq = t >> 4;     // 4 px, 4 rows per thread
    float acc[4][4];
    #pragma unroll
    for (int i = 0; i < 4; i++)
        for (int j = 0; j < 4; j++) acc[i][j] = 0.f;
    for (int ci = 0; ci < 64; ci++) {
        float4 xv = *reinterpret_cast<const float4*>(&xs[ci][pxq * 4]);
        #pragma unroll
        for (int i = 0; i < 4; i++) {
            float wv = wl[rq * 4 + i][ci];
            acc[i][0] += wv * xv.x; acc[i][1] += wv * xv.y;
            acc[i][2] += wv * xv.z; acc[i][3] += wv * xv.w;
        }
    }
    #pragma unroll
    for (int i = 0; i < 4; i++) {
        int co = rq * 4 + i;
        float bb = bias ? bias[co] : 0.f;
        float* p = y + b * (64 * HW) + co * HW + px0 + pxq * 4;
        p[0] = acc[i][0] + bb; p[1] = acc[i][1] + bb;
        p[2] = acc[i][2] + bb; p[3] = acc[i][3] + bb;
    }
}

// ---------------- local 3x3 attention with rel-pos bias (zero-padded k,v; bias added after pad) --
__global__ __launch_bounds__(256) void k_attn(
    const float* __restrict__ q, const float* __restrict__ kc, const float* __restrict__ vc,
    const float* __restrict__ rel_h, const float* __restrict__ rel_w,
    float* __restrict__ out)
{
    int idx = blockIdx.x * 256 + threadIdx.x;     // [b,c,h,w] flat
    if (idx >= NCHW) return;
    int w = idx & 127;
    int h = (idx >> 7) & 127;
    int c = (idx >> 14) & 63;
    float qv = q[idx];
    float s[9], vv[9];
    #pragma unroll
    for (int ki = 0; ki < 3; ki++) {
        #pragma unroll
        for (int kj = 0; kj < 3; kj++) {
            int hh = h + ki - 1, ww = w + kj - 1;
            bool inb = (hh >= 0 && hh < 128 && ww >= 0 && ww < 128);
            int nidx = (idx & ~(HW - 1)) + hh * 128 + ww;
            float kvv = inb ? kc[nidx] : 0.f;
            float vvv = inb ? vc[nidx] : 0.f;
            float rel = (c < 32) ? rel_h[c * 3 + ki] : rel_w[(c - 32) * 3 + kj];
            s[ki * 3 + kj] = qv * (kvv + rel);
            vv[ki * 3 + kj] = vvv;
        }
    }
    float m = s[0];
    #pragma unroll
    for (int i = 1; i < 9; i++) m = fmaxf(m, s[i]);
    float den = 0.f, num = 0.f;
    #pragma unroll
    for (int i = 0; i < 9; i++) { float e = __expf(s[i] - m); den += e; num += e * vv[i]; }
    out[idx] = num / den;
}

// ---------------- forward FFT of out[:,32]: row pass (over w), no scale --------------------------
__global__ __launch_bounds__(128) void k_fftrow_fwd(const float* __restrict__ out, float* __restrict__ R)
{
    int bh = blockIdx.x; int b = bh >> 7, h = bh & 127;   // grid 2*128
    int k = threadIdx.x;
    __shared__ float xr[128];
    xr[k] = out[((b * 64 + 32) << 14) + h * 128 + k];
    __syncthreads();
    float s0, c0; __sincosf(-6.2831853071795864769f * (float)k / 128.0f, &s0, &c0);
    float twr = 1.f, twi = 0.f, ar = 0.f, ai = 0.f;
    for (int n = 0; n < 128; n++) {
        float xv = xr[n];
        ar += xv * twr; ai += xv * twi;
        float nr = twr * c0 - twi * s0;
        twi = twr * s0 + twi * c0; twr = nr;
    }
    float2* Rp = (float2*)R;
    Rp[(b << 14) + h * 128 + k] = make_float2(ar, ai);
}

// ---------------- forward FFT col pass (over h), applies 1/128 ortho scale -----------------------
__global__ __launch_bounds__(128) void k_fftcol_fwd(const float* __restrict__ R, float* __restrict__ F)
{
    int bk = blockIdx.x; int b = bk >> 7, k2 = bk & 127;  // grid 2*128
    int k1 = threadIdx.x;
    __shared__ float2 col[128];
    const float2* Rp = (const float2*)R;
    col[k1] = Rp[(b << 14) + k1 * 128 + k2];
    __syncthreads();
    float s0, c0; __sincosf(-6.2831853071795864769f * (float)k1 / 128.0f, &s0, &c0);
    float twr = 1.f, twi = 0.f, ar = 0.f, ai = 0.f;
    for (int n = 0; n < 128; n++) {
        float2 xv = col[n];
        ar += xv.x * twr - xv.y * twi;
        ai += xv.x * twi + xv.y * twr;
        float nr = twr * c0 - twi * s0;
        twi = twr * s0 + twi * c0; twr = nr;
    }
    float2* Fp = (float2*)F;
    Fp[(b << 14) + k1 * 128 + k2] = make_float2(ar * (1.f / 128.f), ai * (1.f / 128.f));
}

// ---------------- combine conv chain: M = C1*W0*Cv ; bc = C1*(W0*cvb + w0b) + c1b ----------------
// Single block (serial GPU bubble) -> 1024 threads / 16 waves to shrink it.
__global__ __launch_bounds__(1024) void k_combine(
    const float* __restrict__ convv_w, const float* __restrict__ convv_b,
    const float* __restrict__ w0_w, const float* __restrict__ w0_b,
    const float* __restrict__ convv1_w, const float* __restrict__ convv1_b,
    float* __restrict__ M, float* __restrict__ bc)
{
    __shared__ float A[64][64];    // convv_w
    __shared__ float Bm[64][64];   // w0_w
    __shared__ float Cm[64][64];   // convv1_w
    __shared__ float T[64][65];
    __shared__ float t2[64];
    int t = threadIdx.x;
    for (int e = t; e < 4096; e += 1024) {
        int i = e >> 6, j = e & 63;
        A[i][j]  = convv_w[e];
        Bm[i][j] = w0_w[e];
        Cm[i][j] = convv1_w[e];
    }
    __syncthreads();
    for (int e = t; e < 4096; e += 1024) {
        int i = e >> 6, j = e & 63;
        float a = 0.f;
        for (int kk = 0; kk < 64; kk++) a += Bm[i][kk] * A[kk][j];
        T[i][j] = a;
    }
    if (t < 64) {
        float a = 0.f;
        for (int kk = 0; kk < 64; kk++) a += Bm[t][kk] * convv_b[kk];
        t2[t] = a + w0_b[t];
    }
    __syncthreads();
    for (int e = t; e < 4096; e += 1024) {
        int i = e >> 6, j = e & 63;
        float a = 0.f;
        for (int kk = 0; kk < 64; kk++) a += Cm[i][kk] * T[kk][j];
        M[e] = a;
    }
    if (t < 64) {
        float a = 0.f;
        for (int kk = 0; kk < 64; kk++) a += Cm[t][kk] * t2[kk];
        bc[t] = a + convv1_b[t];
    }
}

// ---------------- streaming wsum partial reduction (the 537 MB read) -----------------------------
// Pure streaming: no barriers, no compute phase. grid = 64c * 2half * 16chunk = 2048 blocks.
// Thread owns one float4 column of hw, sums 32 o's (its half). Unroll 16 -> ~32 loads in flight.
// P[half][c][hw] stored as float2 (re,im) pairs for the consumer.
__global__ __launch_bounds__(256) void k_wsum_partial(
    const float* __restrict__ w1r, const float* __restrict__ w1i, float* __restrict__ P)
{
    int blk = blockIdx.x;
    int chunk = blk & 15;
    int half  = (blk >> 4) & 1;
    int c     = blk >> 5;
    int t = threadIdx.x;
    int hw4 = (chunk << 8) + t;                       // float4 index in [0,4096)
    size_t base4 = ((size_t)c << 18) + ((size_t)half << 17) + (size_t)hw4;
    const float4* r4 = reinterpret_cast<const float4*>(w1r) + base4;
    const float4* i4 = reinterpret_cast<const float4*>(w1i) + base4;
    float4 sr = make_float4(0.f, 0.f, 0.f, 0.f);
    float4 si = make_float4(0.f, 0.f, 0.f, 0.f);
    #pragma unroll 16
    for (int o = 0; o < 32; o++) {
        float4 a = r4[o << 12];                       // o-stride = 16384 floats = 4096 float4
        float4 b = i4[o << 12];
        sr.x += a.x; sr.y += a.y; sr.z += a.z; sr.w += a.w;
        si.x += b.x; si.y += b.y; si.z += b.z; si.w += b.w;
    }
    float2* Pp = reinterpret_cast<float2*>(P);
    size_t ob = ((size_t)half << 20) + ((size_t)c << 14) + (size_t)hw4 * 4;
    Pp[ob + 0] = make_float2(sr.x, si.x);
    Pp[ob + 1] = make_float2(sr.y, si.y);
    Pp[ob + 2] = make_float2(sr.z, si.z);
    Pp[ob + 3] = make_float2(sr.w, si.w);
}

// ---------------- spectral multiply + inverse row DFT (reads 16 MB of partials) ------------------
__global__ __launch_bounds__(128) void k_ifftrow(
    const float* __restrict__ P, const float* __restrict__ F, float* __restrict__ Z)
{
    int blk = blockIdx.x; int c = blk >> 7, h = blk & 127;   // grid 64*128
    int t = threadIdx.x;
    __shared__ float2 g0[128];
    __shared__ float2 g1[128];
    const float2* Pp = (const float2*)P;
    const float2* Fp = (const float2*)F;
    float2 p0 = Pp[((size_t)c << 14) + (h << 7) + t];
    float2 p1 = Pp[((size_t)1 << 20) + ((size_t)c << 14) + (h << 7) + t];
    float wr = p0.x + p1.x, wi = p0.y + p1.y;
    float2 f0 = Fp[(h << 7) + t];
    float2 f1 = Fp[(1 << 14) + (h << 7) + t];
    g0[t] = make_float2(f0.x * wr - f0.y * wi, f0.x * wi + f0.y * wr);
    g1[t] = make_float2(f1.x * wr - f1.y * wi, f1.x * wi + f1.y * wr);
    __syncthreads();
    float s0, c0; __sincosf(6.2831853071795864769f * (float)t / 128.0f, &s0, &c0); // + for inverse
    float twr = 1.f, twi = 0.f;
    float a0r = 0.f, a0i = 0.f, a1r = 0.f, a1i = 0.f;
    for (int n = 0; n < 128; n++) {
        float2 u0 = g0[n];
        float2 u1 = g1[n];
        a0r += u0.x * twr - u0.y * twi;
        a0i += u0.x * twi + u0.y * twr;
        a1r += u1.x * twr - u1.y * twi;
        a1i += u1.x * twi + u1.y * twr;
        float nr = twr * c0 - twi * s0;
        twi = twr * s0 + twi * c0; twr = nr;
    }
    float2* Zp = (float2*)Z;
    Zp[((size_t)c << 14) + h * 128 + t]        = make_float2(a0r, a0i);
    Zp[((size_t)(64 + c) << 14) + h * 128 + t] = make_float2(a1r, a1i);
}

// ---------------- inverse col DFT (real part only, i^h symmetry) + fused MSE reduction -----------
// Reads ft directly in [b,y,x,c] layout (no transpose kernel; L2/L3 absorb the strided reads).
__global__ __launch_bounds__(256) void k_ifftcol_mse(
    const float* __restrict__ Zb, const float* __restrict__ out2,
    const float* __restrict__ ft, const float* __restrict__ rate1,
    const float* __restrict__ rate2, float* __restrict__ result)
{
    int blk = blockIdx.x;            // b*256 + c*4 + xc
    int xc = blk & 3;
    int c  = (blk >> 2) & 63;
    int b  = blk >> 8;
    int t = threadIdx.x;
    int xl = t & 31;
    int yq = t >> 5;                 // 0..7
    __shared__ float2 zs[128][33];
    const float2* Zp = (const float2*)Zb;
    int zbase = ((b * 64 + c) << 14) + xc * 32;
    for (int e = t; e < 4096; e += 256) {
        int hh = e >> 5, xx = e & 31;
        zs[hh][xx] = Zp[zbase + hh * 128 + xx];
    }
    __syncthreads();

    // 4 base frequencies y0 = yq + 8j; derived y0+32m via i^h phase classes (h mod 4 buckets)
    float twx[4], twy[4], stx[4], sty[4];
    float Sr[4][4], Si[4][4];
    #pragma unroll
    for (int j = 0; j < 4; j++) {
        int y0 = yq + 8 * j;
        float ss, cc;
        __sincosf(6.2831853071795864769f * (float)y0 / 128.0f, &ss, &cc);
        stx[j] = cc; sty[j] = ss;
        twx[j] = 1.f; twy[j] = 0.f;
        #pragma unroll
        for (int m = 0; m < 4; m++) { Sr[j][m] = 0.f; Si[j][m] = 0.f; }
    }
    for (int h = 0; h < 128; h += 4) {
        #pragma unroll
        for (int m = 0; m < 4; m++) {
            float2 z = zs[h + m][xl];
            #pragma unroll
            for (int j = 0; j < 4; j++) {
                Sr[j][m] += z.x * twx[j] - z.y * twy[j];
                Si[j][m] += z.x * twy[j] + z.y * twx[j];
                float nr = twx[j] * stx[j] - twy[j] * sty[j];
                twy[j]   = twx[j] * sty[j] + twy[j] * stx[j];
                twx[j]   = nr;
            }
        }
    }
    float r1 = rate1[0], r2 = rate2[0];
    int x = xc * 32 + xl;
    int obase = ((b * 64 + c) << 14) + x;
    float part = 0.f;
    #pragma unroll
    for (int j = 0; j < 4; j++) {
        int y0 = yq + 8 * j;
        float o[4];
        o[0] = Sr[j][0] + Sr[j][1] + Sr[j][2] + Sr[j][3];
        o[1] = Sr[j][0] - Si[j][1] - Sr[j][2] + Si[j][3];
        o[2] = Sr[j][0] - Sr[j][1] + Sr[j][2] - Sr[j][3];
        o[3] = Sr[j][0] + Si[j][1] - Sr[j][2] - Si[j][3];
        #pragma unroll
        for (int m = 0; m < 4; m++) {
            int y = y0 + 32 * m;
            float out1 = o[m] * (1.f / 128.f);       // ifft2 ortho scale
            int gi = obase + y * 128;
            float mk = r1 * out1 + r2 * out2[gi];
            int fidx = ((b * HW + y * 128 + x) << 6) + c;
            float d = mk - ft[fidx];
            part += d * d;
        }
    }
    __shared__ float red[256];
    red[t] = part;
    __syncthreads();
    for (int s = 128; s > 0; s >>= 1) {
        if (t < s) red[t] += red[t + s];
        __syncthreads();
    }
    if (t == 0) atomicAdd(result, red[0] * (1.f / 2097152.f));
}

extern "C" void kernel_launch(void* const* d_in, const int* in_sizes, int n_in,
                              void* d_out, int out_size, void* d_ws, size_t ws_size,
                              hipStream_t stream) {
    const float* fs       = (const float*)d_in[0];
    const float* ft       = (const float*)d_in[1];
    const float* w_q      = (const float*)d_in[2];
    const float* w_k      = (const float*)d_in[3];
    const float* w_v      = (const float*)d_in[4];
    const float* rel_h    = (const float*)d_in[5];
    const float* rel_w    = (const float*)d_in[6];
    const float* w1r      = (const float*)d_in[7];
    const float* w1i      = (const float*)d_in[8];
    const float* w0_w     = (const float*)d_in[9];
    const float* w0_b     = (const float*)d_in[10];
    const float* convv_w  = (const float*)d_in[11];
    const float* convv_b  = (const float*)d_in[12];
    const float* convv1_w = (const float*)d_in[13];
    const float* convv1_b = (const float*)d_in[14];
    const float* rate1    = (const float*)d_in[15];
    const float* rate2    = (const float*)d_in[16];

    float* ws = (float*)d_ws;
    float* q    = ws + OFF_Q;
    float* kk   = ws + OFF_K;
    float* vv   = ws + OFF_V;
    float* out  = ws + OFF_OUT;
    float* out2 = ws + OFF_OUT2;
    float* R    = ws + OFF_R;
    float* F    = ws + OFF_F;
    float* M    = ws + OFF_M;
    float* bc   = ws + OFF_BC;
    float* Z    = ws + OFF_Z;
    float* P    = ws + OFF_P;

    // fused q,k,v 1x1 convs
    k_qkv<<<512, 256, 0, stream>>>(fs, w_q, w_k, w_v, q, kk, vv);
    // 3x3 local attention -> out
    k_attn<<<8192, 256, 0, stream>>>(q, kk, vv, rel_h, rel_w, out);
    // forward FFT of out channel 32 (R overlays out2 slot, free until conv chain below)
    k_fftrow_fwd<<<256, 128, 0, stream>>>(out, R);
    k_fftcol_fwd<<<256, 128, 0, stream>>>(R, F);
    // combined conv chain matrix, then out2 = M*out + bc
    k_combine<<<1, 1024, 0, stream>>>(convv_w, convv_b, w0_w, w0_b, convv1_w, convv1_b, M, bc);
    k_gemm64<<<512, 256, 0, stream>>>(out, M, bc, out2);
    // streaming 537 MB wsum reduction (P overlays v/out, both dead after gemm64)
    k_wsum_partial<<<2048, 256, 0, stream>>>(w1r, w1i, P);
    // spectral multiply + inverse row DFT (Z overlays q/k)
    k_ifftrow<<<8192, 128, 0, stream>>>(P, F, Z);
    // inverse col DFT + MSE (reads ft directly)
    hipMemsetAsync(d_out, 0, sizeof(float), stream);
    k_ifftcol_mse<<<512, 256, 0, stream>>>(Z, out2, ft, rate1, rate2, (float*)d_out);
}

// Round 3
// 683.638 us; speedup vs baseline: 1.0312x; 1.0312x over previous
//
#include <hip/hip_runtime.h>
#include <math.h>

// Problem constants: B=2, C=CIN=COUT=64, S=H=W=128, K=3, G=4 (groups are a no-op)
constexpr int HW   = 128 * 128;            // 16384
constexpr int NCHW = 2 * 64 * HW;          // 2097152

// Workspace layout (float element offsets). Z overlays q/k (dead after attn),
// P overlays v/out (dead after gemm64), R overlays out2 (written later).
constexpr size_t OFF_Q    = 0;             // q   [2,64,128,128]
constexpr size_t OFF_K    = 2097152;       // k
constexpr size_t OFF_V    = 4194304;       // v
constexpr size_t OFF_OUT  = 6291456;       // attention out
constexpr size_t OFF_OUT2 = 8388608;       // out2 (earlier: R intermediate)
constexpr size_t OFF_R    = 8388608;
constexpr size_t OFF_F    = 10485760;      // F[b,kh,kw] complex  (65536 floats)
constexpr size_t OFF_M    = 10551296;      // combined conv matrix (4096)
constexpr size_t OFF_BC   = 10555392;      // combined bias (64)
constexpr size_t OFF_Z    = 0;             // Z[b,c,kh,x] complex (4194304 floats)
constexpr size_t OFF_P    = 4194304;       // wsum partials [2][64][16384] complex (4194304 floats)

// ---------------- fused q,k,v 1x1 convs: one fs stage, 3 weight mats in LDS ---------------------
__global__ __launch_bounds__(256) void k_qkv(
    const float* __restrict__ fs,
    const float* __restrict__ w_q, const float* __restrict__ w_k, const float* __restrict__ w_v,
    float* __restrict__ q, float* __restrict__ kk, float* __restrict__ vv)
{
    __shared__ float xs[64][64];       // [ci][px]
    __shared__ float wl[3][64][65];    // [q/k/v][co][ci] padded
    int blk = blockIdx.x;              // 2*256 blocks, 64 px each
    int b = blk >> 8;
    int px0 = (blk & 255) << 6;
    int t = threadIdx.x;
    for (int i = t; i < 4096; i += 256) {
        int r = i >> 6, cix = i & 63;
        wl[0][r][cix] = w_q[i];
        wl[1][r][cix] = w_k[i];
        wl[2][r][cix] = w_v[i];
        xs[r][cix] = fs[b * (64 * HW) + r * HW + px0 + cix];
    }
    __syncthreads();
    int pxq = t & 15, rq = t >> 4;     // 4 px, 4 rows per thread
    float aq[4][4], ak[4][4], av[4][4];
    #pragma unroll
    for (int i = 0; i < 4; i++)
        for (int j = 0; j < 4; j++) { aq[i][j] = 0.f; ak[i][j] = 0.f; av[i][j] = 0.f; }
    for (int ci = 0; ci < 64; ci++) {
        float4 xv = *reinterpret_cast<const float4*>(&xs[ci][pxq * 4]);
        #pragma unroll
        for (int i = 0; i < 4; i++) {
            float wq_ = wl[0][rq * 4 + i][ci];
            float wk_ = wl[1][rq * 4 + i][ci];
            float wv_ = wl[2][rq * 4 + i][ci];
            aq[i][0] += wq_ * xv.x; aq[i][1] += wq_ * xv.y; aq[i][2] += wq_ * xv.z; aq[i][3] += wq_ * xv.w;
            ak[i][0] += wk_ * xv.x; ak[i][1] += wk_ * xv.y; ak[i][2] += wk_ * xv.z; ak[i][3] += wk_ * xv.w;
            av[i][0] += wv_ * xv.x; av[i][1] += wv_ * xv.y; av[i][2] += wv_ * xv.z; av[i][3] += wv_ * xv.w;
        }
    }
    #pragma unroll
    for (int i = 0; i < 4; i++) {
        int co = rq * 4 + i;
        size_t base = (size_t)b * (64 * HW) + (size_t)co * HW + px0 + pxq * 4;
        *reinterpret_cast<float4*>(q  + base) = make_float4(aq[i][0], aq[i][1], aq[i][2], aq[i][3]);
        *reinterpret_cast<float4*>(kk + base) = make_float4(ak[i][0], ak[i][1], ak[i][2], ak[i][3]);
        *reinterpret_cast<float4*>(vv + base) = make_float4(av[i][0], av[i][1], av[i][2], av[i][3]);
    }
}

// ---------------- generic 64x64 1x1-conv GEMM: y[b,co,p] = sum_ci w[co,ci] x[b,ci,p] (+bias) ----
__global__ __launch_bounds__(256) void k_gemm64(
    const float* __restrict__ x, const float* __restrict__ w,
    const float* __restrict__ bias, float* __restrict__ y)
{
    __shared__ float xs[64][64];   // [ci][px]
    __shared__ float wl[64][65];   // [co][ci] padded
    int blk = blockIdx.x;          // 2*256 blocks, 64 px each
    int b = blk >> 8;
    int px0 = (blk & 255) << 6;
    int t = threadIdx.x;
    for (int i = t; i < 4096; i += 256) {
        int r = i >> 6, cix = i & 63;
        wl[r][cix] = w[i];
        xs[r][cix] = x[b * (64 * HW) + r * HW + px0 + cix];
    }
    __syncthreads();
    int pxq = t & 15, rq = t >> 4;     // 4 px, 4 rows per thread
    float acc[4][4];
    #pragma unroll
    for (int i = 0; i < 4; i++)
        for (int j = 0; j < 4; j++) acc[i][j] = 0.f;
    for (int ci = 0; ci < 64; ci++) {
        float4 xv = *reinterpret_cast<const float4*>(&xs[ci][pxq * 4]);
        #pragma unroll
        for (int i = 0; i < 4; i++) {
            float wv = wl[rq * 4 + i][ci];
            acc[i][0] += wv * xv.x; acc[i][1] += wv * xv.y;
            acc[i][2] += wv * xv.z; acc[i][3] += wv * xv.w;
        }
    }
    #pragma unroll
    for (int i = 0; i < 4; i++) {
        int co = rq * 4 + i;
        float bb = bias ? bias[co] : 0.f;
        float* p = y + b * (64 * HW) + co * HW + px0 + pxq * 4;
        p[0] = acc[i][0] + bb; p[1] = acc[i][1] + bb;
        p[2] = acc[i][2] + bb; p[3] = acc[i][3] + bb;
    }
}

// ---------------- local 3x3 attention with rel-pos bias (zero-padded k,v; bias added after pad) --
__global__ __launch_bounds__(256) void k_attn(
    const float* __restrict__ q, const float* __restrict__ kc, const float* __restrict__ vc,
    const float* __restrict__ rel_h, const float* __restrict__ rel_w,
    float* __restrict__ out)
{
    int idx = blockIdx.x * 256 + threadIdx.x;     // [b,c,h,w] flat
    if (idx >= NCHW) return;
    int w = idx & 127;
    int h = (idx >> 7) & 127;
    int c = (idx >> 14) & 63;
    float qv = q[idx];
    float s[9], vv[9];
    #pragma unroll
    for (int ki = 0; ki < 3; ki++) {
        #pragma unroll
        for (int kj = 0; kj < 3; kj++) {
            int hh = h + ki - 1, ww = w + kj - 1;
            bool inb = (hh >= 0 && hh < 128 && ww >= 0 && ww < 128);
            int nidx = (idx & ~(HW - 1)) + hh * 128 + ww;
            float kvv = inb ? kc[nidx] : 0.f;
            float vvv = inb ? vc[nidx] : 0.f;
            float rel = (c < 32) ? rel_h[c * 3 + ki] : rel_w[(c - 32) * 3 + kj];
            s[ki * 3 + kj] = qv * (kvv + rel);
            vv[ki * 3 + kj] = vvv;
        }
    }
    float m = s[0];
    #pragma unroll
    for (int i = 1; i < 9; i++) m = fmaxf(m, s[i]);
    float den = 0.f, num = 0.f;
    #pragma unroll
    for (int i = 0; i < 9; i++) { float e = __expf(s[i] - m); den += e; num += e * vv[i]; }
    out[idx] = num / den;
}

// ---------------- forward FFT of out[:,32]: row pass (over w), no scale --------------------------
__global__ __launch_bounds__(128) void k_fftrow_fwd(const float* __restrict__ out, float* __restrict__ R)
{
    int bh = blockIdx.x; int b = bh >> 7, h = bh & 127;   // grid 2*128
    int k = threadIdx.x;
    __shared__ float xr[128];
    xr[k] = out[((b * 64 + 32) << 14) + h * 128 + k];
    __syncthreads();
    float s0, c0; __sincosf(-6.2831853071795864769f * (float)k / 128.0f, &s0, &c0);
    float twr = 1.f, twi = 0.f, ar = 0.f, ai = 0.f;
    for (int n = 0; n < 128; n++) {
        float xv = xr[n];
        ar += xv * twr; ai += xv * twi;
        float nr = twr * c0 - twi * s0;
        twi = twr * s0 + twi * c0; twr = nr;
    }
    float2* Rp = (float2*)R;
    Rp[(b << 14) + h * 128 + k] = make_float2(ar, ai);
}

// ---------------- forward FFT col pass (over h), applies 1/128 ortho scale -----------------------
__global__ __launch_bounds__(128) void k_fftcol_fwd(const float* __restrict__ R, float* __restrict__ F)
{
    int bk = blockIdx.x; int b = bk >> 7, k2 = bk & 127;  // grid 2*128
    int k1 = threadIdx.x;
    __shared__ float2 col[128];
    const float2* Rp = (const float2*)R;
    col[k1] = Rp[(b << 14) + k1 * 128 + k2];
    __syncthreads();
    float s0, c0; __sincosf(-6.2831853071795864769f * (float)k1 / 128.0f, &s0, &c0);
    float twr = 1.f, twi = 0.f, ar = 0.f, ai = 0.f;
    for (int n = 0; n < 128; n++) {
        float2 xv = col[n];
        ar += xv.x * twr - xv.y * twi;
        ai += xv.x * twi + xv.y * twr;
        float nr = twr * c0 - twi * s0;
        twi = twr * s0 + twi * c0; twr = nr;
    }
    float2* Fp = (float2*)F;
    Fp[(b << 14) + k1 * 128 + k2] = make_float2(ar * (1.f / 128.f), ai * (1.f / 128.f));
}

// ---------------- combine conv chain: M = C1*W0*Cv ; bc = C1*(W0*cvb + w0b) + c1b ----------------
// Single block (serial GPU bubble) -> 1024 threads / 16 waves to shrink it.
__global__ __launch_bounds__(1024) void k_combine(
    const float* __restrict__ convv_w, const float* __restrict__ convv_b,
    const float* __restrict__ w0_w, const float* __restrict__ w0_b,
    const float* __restrict__ convv1_w, const float* __restrict__ convv1_b,
    float* __restrict__ M, float* __restrict__ bc)
{
    __shared__ float A[64][64];    // convv_w
    __shared__ float Bm[64][64];   // w0_w
    __shared__ float Cm[64][64];   // convv1_w
    __shared__ float T[64][65];
    __shared__ float t2[64];
    int t = threadIdx.x;
    for (int e = t; e < 4096; e += 1024) {
        int i = e >> 6, j = e & 63;
        A[i][j]  = convv_w[e];
        Bm[i][j] = w0_w[e];
        Cm[i][j] = convv1_w[e];
    }
    __syncthreads();
    for (int e = t; e < 4096; e += 1024) {
        int i = e >> 6, j = e & 63;
        float a = 0.f;
        for (int kk = 0; kk < 64; kk++) a += Bm[i][kk] * A[kk][j];
        T[i][j] = a;
    }
    if (t < 64) {
        float a = 0.f;
        for (int kk = 0; kk < 64; kk++) a += Bm[t][kk] * convv_b[kk];
        t2[t] = a + w0_b[t];
    }
    __syncthreads();
    for (int e = t; e < 4096; e += 1024) {
        int i = e >> 6, j = e & 63;
        float a = 0.f;
        for (int kk = 0; kk < 64; kk++) a += Cm[i][kk] * T[kk][j];
        M[e] = a;
    }
    if (t < 64) {
        float a = 0.f;
        for (int kk = 0; kk < 64; kk++) a += Cm[t][kk] * t2[kk];
        bc[t] = a + convv1_b[t];
    }
}

// ---------------- streaming wsum partial reduction (the 537 MB read) -----------------------------
// grid = 64c * 2half * 16chunk = 2048 blocks. Thread owns one float4 column of hw, sums 32 o's.
// v2: PHASE-SWIZZLED o order. All blocks walking o in the same order puts the whole device on
// addresses congruent mod 2MB offset by o*64KB -> with 4KB channel/slice interleave only half
// the channels are hit at any instant (measured: 3.33 TB/s ~= copy-ceiling/2). Rotating the o
// start per block spreads concurrent windows across all channels. Pairing o and o+16 (1MB apart)
// doubles loads-in-flight and splits the accumulation chains.
__global__ __launch_bounds__(256) void k_wsum_partial(
    const float* __restrict__ w1r, const float* __restrict__ w1i, float* __restrict__ P)
{
    int blk = blockIdx.x;
    int chunk = blk & 15;
    int half  = (blk >> 4) & 1;
    int c     = blk >> 5;
    int t = threadIdx.x;
    int hw4 = (chunk << 8) + t;                       // float4 index in [0,4096)
    size_t base4 = ((size_t)c << 18) + ((size_t)half << 17) + (size_t)hw4;
    const float4* r4 = reinterpret_cast<const float4*>(w1r) + base4;
    const float4* i4 = reinterpret_cast<const float4*>(w1i) + base4;
    // per-block o-phase: mix chunk/c/half so concurrent blocks cover all o offsets
    int phase = (chunk + c * 5 + half * 3) & 15;
    float4 sr0 = make_float4(0.f, 0.f, 0.f, 0.f);
    float4 si0 = make_float4(0.f, 0.f, 0.f, 0.f);
    float4 sr1 = make_float4(0.f, 0.f, 0.f, 0.f);
    float4 si1 = make_float4(0.f, 0.f, 0.f, 0.f);
    #pragma unroll
    for (int oo = 0; oo < 16; oo++) {
        int o0 = (oo + phase) & 15;                   // [0,16)
        int o1 = o0 + 16;                             // [16,32), 1MB away
        float4 a0 = r4[(size_t)o0 << 12];             // o-stride = 4096 float4 = 64KB
        float4 b0 = i4[(size_t)o0 << 12];
        float4 a1 = r4[(size_t)o1 << 12];
        float4 b1 = i4[(size_t)o1 << 12];
        sr0.x += a0.x; sr0.y += a0.y; sr0.z += a0.z; sr0.w += a0.w;
        si0.x += b0.x; si0.y += b0.y; si0.z += b0.z; si0.w += b0.w;
        sr1.x += a1.x; sr1.y += a1.y; sr1.z += a1.z; sr1.w += a1.w;
        si1.x += b1.x; si1.y += b1.y; si1.z += b1.z; si1.w += b1.w;
    }
    float4 sr = make_float4(sr0.x + sr1.x, sr0.y + sr1.y, sr0.z + sr1.z, sr0.w + sr1.w);
    float4 si = make_float4(si0.x + si1.x, si0.y + si1.y, si0.z + si1.z, si0.w + si1.w);
    float2* Pp = reinterpret_cast<float2*>(P);
    size_t ob = ((size_t)half << 20) + ((size_t)c << 14) + (size_t)hw4 * 4;
    Pp[ob + 0] = make_float2(sr.x, si.x);
    Pp[ob + 1] = make_float2(sr.y, si.y);
    Pp[ob + 2] = make_float2(sr.z, si.z);
    Pp[ob + 3] = make_float2(sr.w, si.w);
}

// ---------------- spectral multiply + inverse row DFT (reads 16 MB of partials) ------------------
__global__ __launch_bounds__(128) void k_ifftrow(
    const float* __restrict__ P, const float* __restrict__ F, float* __restrict__ Z)
{
    int blk = blockIdx.x; int c = blk >> 7, h = blk & 127;   // grid 64*128
    int t = threadIdx.x;
    __shared__ float2 g0[128];
    __shared__ float2 g1[128];
    const float2* Pp = (const float2*)P;
    const float2* Fp = (const float2*)F;
    float2 p0 = Pp[((size_t)c << 14) + (h << 7) + t];
    float2 p1 = Pp[((size_t)1 << 20) + ((size_t)c << 14) + (h << 7) + t];
    float wr = p0.x + p1.x, wi = p0.y + p1.y;
    float2 f0 = Fp[(h << 7) + t];
    float2 f1 = Fp[(1 << 14) + (h << 7) + t];
    g0[t] = make_float2(f0.x * wr - f0.y * wi, f0.x * wi + f0.y * wr);
    g1[t] = make_float2(f1.x * wr - f1.y * wi, f1.x * wi + f1.y * wr);
    __syncthreads();
    float s0, c0; __sincosf(6.2831853071795864769f * (float)t / 128.0f, &s0, &c0); // + for inverse
    float twr = 1.f, twi = 0.f;
    float a0r = 0.f, a0i = 0.f, a1r = 0.f, a1i = 0.f;
    for (int n = 0; n < 128; n++) {
        float2 u0 = g0[n];
        float2 u1 = g1[n];
        a0r += u0.x * twr - u0.y * twi;
        a0i += u0.x * twi + u0.y * twr;
        a1r += u1.x * twr - u1.y * twi;
        a1i += u1.x * twi + u1.y * twr;
        float nr = twr * c0 - twi * s0;
        twi = twr * s0 + twi * c0; twr = nr;
    }
    float2* Zp = (float2*)Z;
    Zp[((size_t)c << 14) + h * 128 + t]        = make_float2(a0r, a0i);
    Zp[((size_t)(64 + c) << 14) + h * 128 + t] = make_float2(a1r, a1i);
}

// ---------------- inverse col DFT (real part only, i^h symmetry) + fused MSE reduction -----------
// Reads ft directly in [b,y,x,c] layout (no transpose kernel; L2/L3 absorb the strided reads).
__global__ __launch_bounds__(256) void k_ifftcol_mse(
    const float* __restrict__ Zb, const float* __restrict__ out2,
    const float* __restrict__ ft, const float* __restrict__ rate1,
    const float* __restrict__ rate2, float* __restrict__ result)
{
    int blk = blockIdx.x;            // b*256 + c*4 + xc
    int xc = blk & 3;
    int c  = (blk >> 2) & 63;
    int b  = blk >> 8;
    int t = threadIdx.x;
    int xl = t & 31;
    int yq = t >> 5;                 // 0..7
    __shared__ float2 zs[128][33];
    const float2* Zp = (const float2*)Zb;
    int zbase = ((b * 64 + c) << 14) + xc * 32;
    for (int e = t; e < 4096; e += 256) {
        int hh = e >> 5, xx = e & 31;
        zs[hh][xx] = Zp[zbase + hh * 128 + xx];
    }
    __syncthreads();

    // 4 base frequencies y0 = yq + 8j; derived y0+32m via i^h phase classes (h mod 4 buckets)
    float twx[4], twy[4], stx[4], sty[4];
    float Sr[4][4], Si[4][4];
    #pragma unroll
    for (int j = 0; j < 4; j++) {
        int y0 = yq + 8 * j;
        float ss, cc;
        __sincosf(6.2831853071795864769f * (float)y0 / 128.0f, &ss, &cc);
        stx[j] = cc; sty[j] = ss;
        twx[j] = 1.f; twy[j] = 0.f;
        #pragma unroll
        for (int m = 0; m < 4; m++) { Sr[j][m] = 0.f; Si[j][m] = 0.f; }
    }
    for (int h = 0; h < 128; h += 4) {
        #pragma unroll
        for (int m = 0; m < 4; m++) {
            float2 z = zs[h + m][xl];
            #pragma unroll
            for (int j = 0; j < 4; j++) {
                Sr[j][m] += z.x * twx[j] - z.y * twy[j];
                Si[j][m] += z.x * twy[j] + z.y * twx[j];
                float nr = twx[j] * stx[j] - twy[j] * sty[j];
                twy[j]   = twx[j] * sty[j] + twy[j] * stx[j];
                twx[j]   = nr;
            }
        }
    }
    float r1 = rate1[0], r2 = rate2[0];
    int x = xc * 32 + xl;
    int obase = ((b * 64 + c) << 14) + x;
    float part = 0.f;
    #pragma unroll
    for (int j = 0; j < 4; j++) {
        int y0 = yq + 8 * j;
        float o[4];
        o[0] = Sr[j][0] + Sr[j][1] + Sr[j][2] + Sr[j][3];
        o[1] = Sr[j][0] - Si[j][1] - Sr[j][2] + Si[j][3];
        o[2] = Sr[j][0] - Sr[j][1] + Sr[j][2] - Sr[j][3];
        o[3] = Sr[j][0] + Si[j][1] - Sr[j][2] - Si[j][3];
        #pragma unroll
        for (int m = 0; m < 4; m++) {
            int y = y0 + 32 * m;
            float out1 = o[m] * (1.f / 128.f);       // ifft2 ortho scale
            int gi = obase + y * 128;
            float mk = r1 * out1 + r2 * out2[gi];
            int fidx = ((b * HW + y * 128 + x) << 6) + c;
            float d = mk - ft[fidx];
            part += d * d;
        }
    }
    __shared__ float red[256];
    red[t] = part;
    __syncthreads();
    for (int s = 128; s > 0; s >>= 1) {
        if (t < s) red[t] += red[t + s];
        __syncthreads();
    }
    if (t == 0) atomicAdd(result, red[0] * (1.f / 2097152.f));
}

extern "C" void kernel_launch(void* const* d_in, const int* in_sizes, int n_in,
                              void* d_out, int out_size, void* d_ws, size_t ws_size,
                              hipStream_t stream) {
    const float* fs       = (const float*)d_in[0];
    const float* ft       = (const float*)d_in[1];
    const float* w_q      = (const float*)d_in[2];
    const float* w_k      = (const float*)d_in[3];
    const float* w_v      = (const float*)d_in[4];
    const float* rel_h    = (const float*)d_in[5];
    const float* rel_w    = (const float*)d_in[6];
    const float* w1r      = (const float*)d_in[7];
    const float* w1i      = (const float*)d_in[8];
    const float* w0_w     = (const float*)d_in[9];
    const float* w0_b     = (const float*)d_in[10];
    const float* convv_w  = (const float*)d_in[11];
    const float* convv_b  = (const float*)d_in[12];
    const float* convv1_w = (const float*)d_in[13];
    const float* convv1_b = (const float*)d_in[14];
    const float* rate1    = (const float*)d_in[15];
    const float* rate2    = (const float*)d_in[16];

    float* ws = (float*)d_ws;
    float* q    = ws + OFF_Q;
    float* kk   = ws + OFF_K;
    float* vv   = ws + OFF_V;
    float* out  = ws + OFF_OUT;
    float* out2 = ws + OFF_OUT2;
    float* R    = ws + OFF_R;
    float* F    = ws + OFF_F;
    float* M    = ws + OFF_M;
    float* bc   = ws + OFF_BC;
    float* Z    = ws + OFF_Z;
    float* P    = ws + OFF_P;

    // fused q,k,v 1x1 convs
    k_qkv<<<512, 256, 0, stream>>>(fs, w_q, w_k, w_v, q, kk, vv);
    // 3x3 local attention -> out
    k_attn<<<8192, 256, 0, stream>>>(q, kk, vv, rel_h, rel_w, out);
    // forward FFT of out channel 32 (R overlays out2 slot, free until conv chain below)
    k_fftrow_fwd<<<256, 128, 0, stream>>>(out, R);
    k_fftcol_fwd<<<256, 128, 0, stream>>>(R, F);
    // combined conv chain matrix, then out2 = M*out + bc
    k_combine<<<1, 1024, 0, stream>>>(convv_w, convv_b, w0_w, w0_b, convv1_w, convv1_b, M, bc);
    k_gemm64<<<512, 256, 0, stream>>>(out, M, bc, out2);
    // streaming 537 MB wsum reduction (P overlays v/out, both dead after gemm64)
    k_wsum_partial<<<2048, 256, 0, stream>>>(w1r, w1i, P);
    // spectral multiply + inverse row DFT (Z overlays q/k)
    k_ifftrow<<<8192, 128, 0, stream>>>(P, F, Z);
    // inverse col DFT + MSE (reads ft directly)
    hipMemsetAsync(d_out, 0, sizeof(float), stream);
    k_ifftcol_mse<<<512, 256, 0, stream>>>(Z, out2, ft, rate1, rate2, (float*)d_out);
}